// Round 10
// baseline (826.347 us; speedup 1.0000x reference)
//
#include <hip/hip_runtime.h>
#include <stdint.h>

#define EPS 1e-5f

typedef __attribute__((ext_vector_type(4))) float f32x4;
typedef __attribute__((ext_vector_type(8))) short bf16x8_t;

__device__ __forceinline__ unsigned short f2bf(float x) {
    unsigned u = __float_as_uint(x);
    unsigned r = (u + 0x7FFFu + ((u >> 16) & 1u)) >> 16;
    return (unsigned short)r;
}
__device__ __forceinline__ float bf2f(unsigned short b) {
    return __uint_as_float(((unsigned)b) << 16);
}
// packed 2xf32 -> 2xbf16 in one VALU op (gfx950)
__device__ __forceinline__ unsigned cvtpk(float a, float b) {
    unsigned r;
    asm("v_cvt_pk_bf16_f32 %0, %1, %2" : "=v"(r) : "v"(a), "v"(b));
    return r;
}
union U8 { unsigned u[4]; bf16x8_t v; };

// ---------------------------------------------------------------------------
// K0: P[N x 256] = x[N x 128] @ Wc^T ; Wc[j] = (j<128) ? W1[j][0:128] : W1[j-128][128:256]
// ---------------------------------------------------------------------------
__global__ __launch_bounds__(256) void gemm_p_kernel(const float* __restrict__ x,
    const float* __restrict__ W1, float* __restrict__ P, int Nn)
{
    __shared__ float As[64][36];
    __shared__ float Bt[32][68];
    int tid = threadIdx.x;
    int tx = tid & 15, ty = tid >> 4;
    int m0 = blockIdx.x * 64;
    int n0 = blockIdx.y * 64;
    float acc[4][4] = {};
    for (int kc = 0; kc < 128; kc += 32) {
        for (int t = tid; t < 512; t += 256) {
            int r = t >> 3, q = t & 7;
            int m = m0 + r;
            float4 v = make_float4(0.f, 0.f, 0.f, 0.f);
            if (m < Nn) v = *(const float4*)&x[(size_t)m * 128 + kc + q * 4];
            *(float4*)&As[r][q * 4] = v;
        }
        for (int t = tid; t < 512; t += 256) {
            int r = t >> 3, q = t & 7;
            int j = n0 + r;
            const float* s = (j < 128) ? &W1[(size_t)j * 256 + kc + q * 4]
                                       : &W1[(size_t)(j - 128) * 256 + 128 + kc + q * 4];
            float4 w = *(const float4*)s;
            Bt[q * 4 + 0][r] = w.x; Bt[q * 4 + 1][r] = w.y;
            Bt[q * 4 + 2][r] = w.z; Bt[q * 4 + 3][r] = w.w;
        }
        __syncthreads();
        #pragma unroll
        for (int kk = 0; kk < 32; kk += 4) {
            float avf[4][4];
            #pragma unroll
            for (int i = 0; i < 4; i++)
                *(float4*)&avf[i][0] = *(const float4*)&As[ty * 4 + i][kk];
            #pragma unroll
            for (int s = 0; s < 4; s++) {
                float4 b = *(const float4*)&Bt[kk + s][tx * 4];
                float bb[4] = {b.x, b.y, b.z, b.w};
                #pragma unroll
                for (int i = 0; i < 4; i++)
                    #pragma unroll
                    for (int j = 0; j < 4; j++)
                        acc[i][j] = fmaf(avf[i][s], bb[j], acc[i][j]);
            }
        }
        __syncthreads();
    }
    #pragma unroll
    for (int i = 0; i < 4; i++) {
        int m = m0 + ty * 4 + i;
        if (m < Nn)
            *(float4*)&P[(size_t)m * 256 + n0 + tx * 4] =
                make_float4(acc[i][0], acc[i][1], acc[i][2], acc[i][3]);
    }
}

// ---------------------------------------------------------------------------
__global__ void convert_w2_kernel(const float* __restrict__ W2, unsigned short* __restrict__ W2bf)
{
    int i = blockIdx.x * 256 + threadIdx.x;
    W2bf[i] = f2bf(W2[i]);
}

// ---------------------------------------------------------------------------
// K1: BN1 stats of h1[e][c] = Ps[src[e]][c] + Pd[dst[e]][c]  (raw P, pre-scale)
// ---------------------------------------------------------------------------
__global__ __launch_bounds__(256) void stats1_kernel(const float* __restrict__ P,
    const int* __restrict__ src, const int* __restrict__ dst, int E,
    float* __restrict__ gsum, float* __restrict__ gsq)
{
    int tid = threadIdx.x;
    int cg = tid & 31, rg = tid >> 5;
    int c0 = cg * 4;
    f32x4 s = {0.f, 0.f, 0.f, 0.f}, q = {0.f, 0.f, 0.f, 0.f};
    int stride = gridDim.x * 8;
    for (int e = blockIdx.x * 8 + rg; e < E; e += stride) {
        int sN = src[e], dN = dst[e];
        f32x4 v = *(const f32x4*)&P[(size_t)sN * 256 + c0]
                + *(const f32x4*)&P[(size_t)dN * 256 + 128 + c0];
        s += v; q += v * v;
    }
    __shared__ float shs[8][128], shq[8][128];
    *(f32x4*)&shs[rg][c0] = s;
    *(f32x4*)&shq[rg][c0] = q;
    __syncthreads();
    if (tid < 128) {
        float ts = 0.f, tq = 0.f;
        #pragma unroll
        for (int g = 0; g < 8; g++) { ts += shs[g][tid]; tq += shq[g][tid]; }
        atomicAdd(&gsum[tid], ts);
        atomicAdd(&gsq[tid], tq);
    }
}

// ---------------------------------------------------------------------------
__global__ void finalize_kernel(const float* __restrict__ gsum, const float* __restrict__ gsq,
    const float* __restrict__ gamma, const float* __restrict__ beta, float Einv,
    float* __restrict__ a, float* __restrict__ cc)
{
    int c = threadIdx.x;
    float mean = gsum[c] * Einv;
    float var  = gsq[c] * Einv - mean * mean;
    float ai = gamma[c] / sqrtf(var + EPS);
    a[c] = ai;
    cc[c] = beta[c] - mean * ai;
}

// ---------------------------------------------------------------------------
// Pre-scale P in place: src half *= a1[c]; dst half = *a1[c] + c1[c].
// After this, U = relu(Ps'[c] + Pd''[c]) per edge — no per-edge BN math.
// ---------------------------------------------------------------------------
__global__ __launch_bounds__(256) void prescale_kernel(float* __restrict__ P,
    const float* __restrict__ a1, const float* __restrict__ c1, int Nn)
{
    long long i = (long long)blockIdx.x * 256 + threadIdx.x;   // unit = f32x4
    long long total = (long long)Nn * 64;
    long long stride = (long long)gridDim.x * 256;
    for (; i < total; i += stride) {
        int col = (int)((i & 63) * 4);
        f32x4 v = *(f32x4*)&P[i * 4];
        if (col < 128) {
            v *= *(const f32x4*)&a1[col];
        } else {
            v = v * (*(const f32x4*)&a1[col - 128]) + (*(const f32x4*)&c1[col - 128]);
        }
        *(f32x4*)&P[i * 4] = v;
    }
}

// ---------------------------------------------------------------------------
// Counting sort by dst: histogram, 3-dispatch exclusive scan, permutation
// ---------------------------------------------------------------------------
__global__ __launch_bounds__(256) void hist_kernel(const int* __restrict__ dst, int E,
    int* __restrict__ cnt)
{
    int i = blockIdx.x * 256 + threadIdx.x;
    int stride = gridDim.x * 256;
    for (; i < E; i += stride) atomicAdd(&cnt[dst[i]], 1);
}

__global__ __launch_bounds__(256) void scan_sum_kernel(const int* __restrict__ cnt, int Nn,
    int* __restrict__ bsum)
{
    int t = threadIdx.x, b = blockIdx.x;
    int i = b * 256 + t;
    __shared__ int sh[256];
    sh[t] = (i < Nn) ? cnt[i] : 0;
    __syncthreads();
    for (int d = 128; d > 0; d >>= 1) { if (t < d) sh[t] += sh[t + d]; __syncthreads(); }
    if (t == 0) bsum[b] = sh[0];
}

__global__ __launch_bounds__(256) void scan_base_kernel(const int* __restrict__ bsum, int nb,
    int* __restrict__ bbase)
{
    int t = threadIdx.x;
    int v = (t < nb) ? bsum[t] : 0;
    __shared__ int sh[256];
    sh[t] = v;
    __syncthreads();
    for (int d = 1; d < 256; d <<= 1) {
        int x = (t >= d) ? sh[t - d] : 0;
        __syncthreads();
        sh[t] += x;
        __syncthreads();
    }
    if (t < nb) bbase[t] = sh[t] - v;   // exclusive
}

__global__ __launch_bounds__(256) void scan_offs_kernel(const int* __restrict__ cnt,
    const int* __restrict__ bbase, int Nn, int E, int* __restrict__ offs)
{
    int t = threadIdx.x, b = blockIdx.x;
    int i = b * 256 + t;
    int v = (i < Nn) ? cnt[i] : 0;
    __shared__ int sh[256];
    sh[t] = v;
    __syncthreads();
    for (int d = 1; d < 256; d <<= 1) {
        int x = (t >= d) ? sh[t - d] : 0;
        __syncthreads();
        sh[t] += x;
        __syncthreads();
    }
    if (i < Nn) offs[i] = bbase[b] + sh[t] - v;
    if (i == 0 && b == 0) offs[Nn] = E;
}

__global__ __launch_bounds__(256) void perm_kernel(const int* __restrict__ src,
    const int* __restrict__ dst, int E, const int* __restrict__ offs, int* __restrict__ pos,
    int* __restrict__ srcs, int* __restrict__ dsts)
{
    int i = blockIdx.x * 256 + threadIdx.x;
    int stride = gridDim.x * 256;
    for (; i < E; i += stride) {
        int d = dst[i];
        int slot = offs[d] + atomicAdd(&pos[d], 1);
        srcs[slot] = src[i];
        dsts[slot] = d;
    }
}

// ---------------------------------------------------------------------------
// K3: MFMA edge GEMM2 on dst-sorted edges, pre-scaled P.
// A-row = relu(Ps'[s]+Pd''[d]) as single bf16 (cvt_pk). 32 MFMA/wave.
// MODE 0: linear h2s store + BN2 stats.  MODE 1: stats only.  MODE 2: scatter.
// ---------------------------------------------------------------------------
template<int MODE>
__global__ __launch_bounds__(256) void edge_mfma_kernel(
    const float* __restrict__ P, const int* __restrict__ src, const int* __restrict__ dst,
    const unsigned short* __restrict__ W2bf,
    unsigned short* __restrict__ h2s, float* __restrict__ gsum, float* __restrict__ gsq,
    const float* __restrict__ a2, const float* __restrict__ c2,
    float* __restrict__ out, int E)
{
    int tid = threadIdx.x;
    int wid = tid >> 6, lane = tid & 63;
    int lr = lane & 15, lk = lane >> 4;        // A row / B col = lr, k-group = lk
    int wm = wid >> 1, wn = wid & 1;
    int e0 = blockIdx.x * 64;
    int m0w = wm * 32, n0w = wn * 64;

    __shared__ int didx[64];                   // MODE 2 epilogue only
    if (MODE == 2 && tid < 64) {
        int e = min(e0 + tid, E - 1);
        didx[tid] = dst[e];
    }

    int e_mi[2], s_mi[2], d_mi[2];
    #pragma unroll
    for (int mi = 0; mi < 2; mi++) {
        int e = e0 + m0w + mi * 16 + lr;
        e_mi[mi] = e;
        int ec = min(e, E - 1);
        s_mi[mi] = src[ec];
        d_mi[mi] = dst[ec];
    }

    f32x4 acc[2][4];
    #pragma unroll
    for (int mi = 0; mi < 2; mi++)
        #pragma unroll
        for (int nj = 0; nj < 4; nj++) {
            f32x4 z = {0.f, 0.f, 0.f, 0.f};
            acc[mi][nj] = z;
        }

    #pragma unroll
    for (int kt = 0; kt < 4; kt++) {
        int c0 = kt * 32 + lk * 8;
        bf16x8_t b[4];
        #pragma unroll
        for (int nj = 0; nj < 4; nj++)
            b[nj] = *(const bf16x8_t*)&W2bf[(size_t)(n0w + nj * 16 + lr) * 128 + c0];
        #pragma unroll
        for (int mi = 0; mi < 2; mi++) {
            const float* ps = &P[(size_t)s_mi[mi] * 256 + c0];
            const float* pd = &P[(size_t)d_mi[mi] * 256 + 128 + c0];
            f32x4 h0 = *(const f32x4*)ps + *(const f32x4*)pd;
            f32x4 h1 = *(const f32x4*)(ps + 4) + *(const f32x4*)(pd + 4);
            float vm = (e_mi[mi] < E) ? 1.f : 0.f;
            U8 au;
            au.u[0] = cvtpk(fmaxf(h0[0], 0.f) * vm, fmaxf(h0[1], 0.f) * vm);
            au.u[1] = cvtpk(fmaxf(h0[2], 0.f) * vm, fmaxf(h0[3], 0.f) * vm);
            au.u[2] = cvtpk(fmaxf(h1[0], 0.f) * vm, fmaxf(h1[1], 0.f) * vm);
            au.u[3] = cvtpk(fmaxf(h1[2], 0.f) * vm, fmaxf(h1[3], 0.f) * vm);
            #pragma unroll
            for (int nj = 0; nj < 4; nj++)
                acc[mi][nj] = __builtin_amdgcn_mfma_f32_16x16x32_bf16(au.v, b[nj], acc[mi][nj], 0, 0, 0);
        }
    }
    // D layout (m89-verified): col = lane&15 (=lr), row = lk*4 + reg.

    if (MODE == 0 || MODE == 1) {
        __shared__ float reds[2][128], redq[2][128];
        #pragma unroll
        for (int nj = 0; nj < 4; nj++) {
            float sa = 0.f, sq = 0.f;
            #pragma unroll
            for (int mi = 0; mi < 2; mi++)
                #pragma unroll
                for (int r = 0; r < 4; r++) {
                    float v = acc[mi][nj][r];
                    sa += v; sq += v * v;
                }
            sa += __shfl_xor(sa, 16); sa += __shfl_xor(sa, 32);
            sq += __shfl_xor(sq, 16); sq += __shfl_xor(sq, 32);
            if (lk == 0) {
                reds[wm][n0w + nj * 16 + lr] = sa;
                redq[wm][n0w + nj * 16 + lr] = sq;
            }
        }
        if (MODE == 0) {
            __shared__ unsigned short ush[64][136];
            #pragma unroll
            for (int mi = 0; mi < 2; mi++)
                #pragma unroll
                for (int nj = 0; nj < 4; nj++)
                    #pragma unroll
                    for (int r = 0; r < 4; r++)
                        ush[m0w + mi * 16 + lk * 4 + r][n0w + nj * 16 + lr] = f2bf(acc[mi][nj][r]);
            __syncthreads();
            if (tid < 128) {
                atomicAdd(&gsum[tid], reds[0][tid] + reds[1][tid]);
                atomicAdd(&gsq[tid],  redq[0][tid] + redq[1][tid]);
            }
            // sorted order => linear store: row e0+row of h2s
            #pragma unroll
            for (int it = 0; it < 4; it++) {
                int chunk = it * 256 + tid;
                int row = chunk >> 4, q = chunk & 15;
                bf16x8_t v = *(const bf16x8_t*)&ush[row][q * 8];
                if (e0 + row < E)
                    *(bf16x8_t*)&h2s[(size_t)(e0 + row) * 128 + q * 8] = v;
            }
        } else {
            __syncthreads();
            if (tid < 128) {
                atomicAdd(&gsum[tid], reds[0][tid] + reds[1][tid]);
                atomicAdd(&gsq[tid],  redq[0][tid] + redq[1][tid]);
            }
        }
    }
    if (MODE == 2) {
        __syncthreads();   // didx visible
        float a2v[4], c2v[4];
        #pragma unroll
        for (int nj = 0; nj < 4; nj++) {
            int col = n0w + nj * 16 + lr;
            a2v[nj] = a2[col]; c2v[nj] = c2[col];
        }
        #pragma unroll
        for (int mi = 0; mi < 2; mi++)
            #pragma unroll
            for (int r = 0; r < 4; r++) {
                int row = m0w + mi * 16 + lk * 4 + r;
                if (e0 + row < E) {
                    int dn = didx[row];
                    #pragma unroll
                    for (int nj = 0; nj < 4; nj++) {
                        float y = fmaxf(fmaf(a2v[nj], acc[mi][nj][r], c2v[nj]), 0.f);
                        if (y > 0.f) atomicAdd(&out[(size_t)dn * 128 + n0w + nj * 16 + lr], y);
                    }
                }
            }
    }
}

// ---------------------------------------------------------------------------
// K5: segmented reduction (one wave per node, no atomics)
// ---------------------------------------------------------------------------
__global__ __launch_bounds__(256) void segred_kernel(const unsigned short* __restrict__ h2s,
    const int* __restrict__ offs, const float* __restrict__ a2, const float* __restrict__ c2,
    float* __restrict__ out, int Nn)
{
    int node = blockIdx.x * 4 + (threadIdx.x >> 6);
    if (node >= Nn) return;
    int lane = threadIdx.x & 63;
    int c0 = lane * 2;
    float aa0 = a2[c0], aa1 = a2[c0 + 1];
    float cb0 = c2[c0], cb1 = c2[c0 + 1];
    int rb = offs[node], re = offs[node + 1];
    float s0 = 0.f, s1 = 0.f;
    for (int r = rb; r < re; ++r) {
        unsigned v = *(const unsigned*)&h2s[(size_t)r * 128 + c0];
        s0 += fmaxf(fmaf(aa0, bf2f((unsigned short)(v & 0xffffu)), cb0), 0.f);
        s1 += fmaxf(fmaf(aa1, bf2f((unsigned short)(v >> 16)), cb1), 0.f);
    }
    *(float2*)&out[(size_t)node * 128 + c0] = make_float2(s0, s1);
}

// ---------------------------------------------------------------------------
extern "C" void kernel_launch(void* const* d_in, const int* in_sizes, int n_in,
                              void* d_out, int out_size, void* d_ws, size_t ws_size,
                              hipStream_t stream)
{
    const float* x   = (const float*)d_in[0];
    const int*   ei  = (const int*)d_in[1];
    const float* W1  = (const float*)d_in[2];
    // d_in[3] = b1: unused (BN shift-invariance)
    const float* g1  = (const float*)d_in[4];
    const float* be1 = (const float*)d_in[5];
    const float* W2  = (const float*)d_in[6];
    // d_in[7] = b2: unused
    const float* g2  = (const float*)d_in[8];
    const float* be2 = (const float*)d_in[9];
    float* out = (float*)d_out;

    int Nn = in_sizes[0] / 128;
    int E  = in_sizes[1] / 2;
    const int* srcI = ei;
    const int* dstI = ei + E;

    float* ws    = (float*)d_ws;
    float* gsum1 = ws;        float* gsq1 = ws + 128;
    float* gsum2 = ws + 256;  float* gsq2 = ws + 384;
    float* a1    = ws + 512;  float* c1   = ws + 640;
    float* a2    = ws + 768;  float* c2   = ws + 896;
    unsigned short* W2bf = (unsigned short*)(ws + 1024);   // 16384 ushort
    float* P     = ws + 9216;
    unsigned short* h2s = (unsigned short*)(P + (size_t)Nn * 256);
    int* cnt  = (int*)(h2s + (size_t)E * 128);
    int* pos  = cnt + Nn;
    int* offs = pos + Nn;          // Nn+1
    int* bsum = offs + Nn + 1;     // 256
    int* bbase = bsum + 256;       // 256
    int* srcs = bbase + 256;       // E
    int* dsts = srcs + E;          // E
    size_t need_mat = (size_t)9216 * 4 + (size_t)Nn * 1024 + (size_t)E * 256
                    + ((size_t)3 * Nn + 513 + 512 + (size_t)2 * E) * 4;
    bool mat = (ws_size >= need_mat);
    int nb = (Nn + 255) / 256;     // scan blocks (196 for N=50k; must be <=256)

    hipMemsetAsync(ws, 0, 512 * sizeof(float), stream);                 // stats accum
    hipMemsetAsync(out, 0, (size_t)out_size * sizeof(float), stream);

    dim3 b256(256);
    convert_w2_kernel<<<64, b256, 0, stream>>>(W2, W2bf);
    gemm_p_kernel<<<dim3((Nn + 63) / 64, 4), b256, 0, stream>>>(x, W1, P, Nn);

    int gE = (E + 63) / 64;
    if (mat && nb <= 256) {
        hipMemsetAsync(cnt, 0, (size_t)2 * Nn * sizeof(int), stream);   // cnt + pos
        hist_kernel<<<1024, b256, 0, stream>>>(dstI, E, cnt);
        scan_sum_kernel<<<nb, b256, 0, stream>>>(cnt, Nn, bsum);
        scan_base_kernel<<<1, b256, 0, stream>>>(bsum, nb, bbase);
        scan_offs_kernel<<<nb, b256, 0, stream>>>(cnt, bbase, Nn, E, offs);
        perm_kernel<<<1024, b256, 0, stream>>>(srcI, dstI, E, offs, pos, srcs, dsts);
        stats1_kernel<<<4096, b256, 0, stream>>>(P, srcs, dsts, E, gsum1, gsq1);
        finalize_kernel<<<1, 128, 0, stream>>>(gsum1, gsq1, g1, be1, 1.0f / (float)E, a1, c1);
        prescale_kernel<<<2048, b256, 0, stream>>>(P, a1, c1, Nn);
        edge_mfma_kernel<0><<<gE, b256, 0, stream>>>(P, srcs, dsts, W2bf,
            h2s, gsum2, gsq2, nullptr, nullptr, nullptr, E);
        finalize_kernel<<<1, 128, 0, stream>>>(gsum2, gsq2, g2, be2, 1.0f / (float)E, a2, c2);
        segred_kernel<<<(Nn + 3) / 4, b256, 0, stream>>>(h2s, offs, a2, c2, out, Nn);
    } else {
        stats1_kernel<<<4096, b256, 0, stream>>>(P, srcI, dstI, E, gsum1, gsq1);
        finalize_kernel<<<1, 128, 0, stream>>>(gsum1, gsq1, g1, be1, 1.0f / (float)E, a1, c1);
        prescale_kernel<<<2048, b256, 0, stream>>>(P, a1, c1, Nn);
        edge_mfma_kernel<1><<<gE, b256, 0, stream>>>(P, srcI, dstI, W2bf,
            nullptr, gsum2, gsq2, nullptr, nullptr, nullptr, E);
        finalize_kernel<<<1, 128, 0, stream>>>(gsum2, gsq2, g2, be2, 1.0f / (float)E, a2, c2);
        edge_mfma_kernel<2><<<gE, b256, 0, stream>>>(P, srcI, dstI, W2bf,
            nullptr, nullptr, nullptr, a2, c2, out, E);
    }
}